// Round 9
// baseline (339.001 us; speedup 1.0000x reference)
//
#include <hip/hip_runtime.h>
#include <hip/hip_bf16.h>

#define N_NODES 50000
#define N_EDGES 800000
#define IN_CH 256
#define HID 256
#define OUT_CH 128
#define N_GRAPHS 64
#define SCAN_BLOCKS 196   // ceil(50001/256)
#define M_PAD 50048       // 391 * 128
#define POOL_CHUNK 32
#define POOL_BLOCKS ((N_NODES + POOL_CHUNK - 1) / POOL_CHUNK)
#define AGG1_HALF 12500   // blocks per plane (4 nodes/block, 12500*4 = 50000)

typedef __bf16 bf16x8 __attribute__((ext_vector_type(8)));
typedef float f32x4 __attribute__((ext_vector_type(4)));
typedef unsigned short u16x8 __attribute__((ext_vector_type(8)));

// bf16 <-> f32 helpers (RNE on pack)
__device__ __forceinline__ float bf2f(unsigned short u) {
    union { unsigned int i; float f; } x; x.i = ((unsigned int)u) << 16; return x.f;
}
__device__ __forceinline__ unsigned short f2bf(float f) {
    union { float f; unsigned int i; } x; x.f = f;
    unsigned int r = x.i + 0x7FFFu + ((x.i >> 16) & 1u);
    return (unsigned short)(r >> 16);
}

__device__ __forceinline__ void load16(const void* g, void* l) {
    __builtin_amdgcn_global_load_lds(
        (const __attribute__((address_space(1))) void*)g,
        (__attribute__((address_space(3))) void*)l, 16, 0, 0);
}

// final rowptr = block-local exclusive + per-256-chunk offset
__device__ __forceinline__ int rp(const int* __restrict__ rl,
                                  const int* __restrict__ boff, int i) {
    return rl[i] + boff[i >> 8];
}

// ---------------------------------------------------------------------------
// CSR build: histogram, scan_a (block-local), merged scan_b+cvt_w, fill.
// ---------------------------------------------------------------------------
__global__ __launch_bounds__(256) void count_kernel(const int* __restrict__ ei,
                                                    int* __restrict__ cnt) {
    int e = blockIdx.x * 256 + threadIdx.x;
    if (e < N_EDGES) atomicAdd(&cnt[ei[N_EDGES + e]], 1);
}

// block-local exclusive scan over 256-chunks; also emits dinv/invdeg.
// Writes rl[i] for i <= N_NODES (v=0 beyond) so e1 lookups work at the edge.
__global__ __launch_bounds__(256) void scan_a_kernel(const int* __restrict__ cnt,
                                                     int* __restrict__ rl,
                                                     int* __restrict__ blocksum,
                                                     float* __restrict__ dinv,
                                                     float* __restrict__ invdeg) {
    __shared__ int tmp[256];
    int t = threadIdx.x;
    int i = blockIdx.x * 256 + t;
    int v = (i < N_NODES) ? cnt[i] : 0;
    int x = v;
    tmp[t] = x;
    __syncthreads();
#pragma unroll
    for (int off = 1; off < 256; off <<= 1) {
        int y = (t >= off) ? tmp[t - off] : 0;
        __syncthreads();
        x += y;
        tmp[t] = x;
        __syncthreads();
    }
    if (i <= N_NODES) rl[i] = x - v;
    if (i < N_NODES) {
        float d = (float)v + 1.0f;         // +1 self loop
        dinv[i] = rsqrtf(d);
        invdeg[i] = 1.0f / d;
    }
    if (t == 255) blocksum[blockIdx.x] = x;
}

// blocks 0..383: W1/W2 f32 -> bf16 transposed [N][K].
// block 384: exclusive scan of the 196 block sums -> blockoff.
__global__ __launch_bounds__(256) void scanb_cvtw_kernel(
        const int* __restrict__ blocksum, int* __restrict__ blockoff,
        const float* __restrict__ W1, const float* __restrict__ W2,
        unsigned short* __restrict__ w1t, unsigned short* __restrict__ w2t) {
    int t = threadIdx.x;
    if (blockIdx.x < 384) {
        int i = blockIdx.x * 256 + t;                 // 0 .. 98303
        if (i < HID * IN_CH) {                        // W1t[n][k] = W1[k][n]
            int n = i >> 8, k = i & 255;
            w1t[i] = f2bf(W1[k * HID + n]);
        } else {                                      // W2t[n][k] = W2[k][n]
            int j = i - HID * IN_CH;
            int n = j >> 8, k = j & 255;
            w2t[j] = f2bf(W2[k * OUT_CH + n]);
        }
        return;
    }
    __shared__ int tmp[256];
    int v = (t < SCAN_BLOCKS) ? blocksum[t] : 0;
    int x = v;
    tmp[t] = x;
    __syncthreads();
#pragma unroll
    for (int off = 1; off < 256; off <<= 1) {
        int y = (t >= off) ? tmp[t - off] : 0;
        __syncthreads();
        x += y;
        tmp[t] = x;
        __syncthreads();
    }
    if (t < SCAN_BLOCKS) blockoff[t] = x - v;
}

__global__ __launch_bounds__(256) void fill_kernel(const int* __restrict__ ei,
                                                   const int* __restrict__ rl,
                                                   const int* __restrict__ boff,
                                                   int* __restrict__ fillp,
                                                   int2* __restrict__ edge2,
                                                   const float* __restrict__ dinv) {
    int e = blockIdx.x * 256 + threadIdx.x;
    if (e >= N_EDGES) return;
    int s = ei[e];
    int d = ei[N_EDGES + e];
    int p = rp(rl, boff, d) + atomicAdd(&fillp[d], 1);
    float w = dinv[s] * dinv[d];
    edge2[p] = make_int2(s, __float_as_int(w));
}

// ---------------------------------------------------------------------------
// bf16 MFMA GEMM (bf16 A): C = A @ Bt^T interleaved. 128x128 tile, 4 waves
// 2x2, each 64x64 = 4x4 mfma_f32_16x16x32_bf16. global_load_lds staging.
// ---------------------------------------------------------------------------
__global__ __launch_bounds__(256) void gemm_mfma_kernel(
        const unsigned short* __restrict__ A,
        const unsigned short* __restrict__ Bt,
        unsigned short* __restrict__ C,
        int N) {
    const int K = 256;
    __shared__ char As[8192];   // [128 rows][32 bf16], 16B chunks XOR-swizzled
    __shared__ char Bs[8192];
    int tid = threadIdx.x;
    int bm = blockIdx.x * 128;
    int bn = blockIdx.y * 128;
    int lane = tid & 63, wave = tid >> 6;
    int lane15 = lane & 15, quad = lane >> 4;
    int wm0 = (wave >> 1) << 6;
    int wn0 = (wave & 1) << 6;

    int s1 = tid, s2 = tid + 256;
    int r1 = s1 >> 2, q1 = (s1 & 3) ^ ((r1 >> 1) & 3);
    int r2 = s2 >> 2, q2 = (s2 & 3) ^ ((r2 >> 1) & 3);
    const char* gA1 = (const char*)(A + (size_t)(bm + r1) * K) + (q1 << 4);
    const char* gA2 = (const char*)(A + (size_t)(bm + r2) * K) + (q2 << 4);
    const char* gB1 = (const char*)(Bt + (size_t)(bn + r1) * K) + (q1 << 4);
    const char* gB2 = (const char*)(Bt + (size_t)(bn + r2) * K) + (q2 << 4);
    char* lA1 = As + (wave << 10);
    char* lA2 = As + 4096 + (wave << 10);
    char* lB1 = Bs + (wave << 10);
    char* lB2 = Bs + 4096 + (wave << 10);

    int swm = (lane15 >> 1) & 3;
    f32x4 acc[4][4];
#pragma unroll
    for (int mt = 0; mt < 4; mt++)
#pragma unroll
        for (int nt = 0; nt < 4; nt++)
            acc[mt][nt] = (f32x4){0.f, 0.f, 0.f, 0.f};

    for (int k0 = 0; k0 < K; k0 += 32) {
        __syncthreads();
        load16(gA1 + (k0 << 1), lA1);
        load16(gA2 + (k0 << 1), lA2);
        load16(gB1 + (k0 << 1), lB1);
        load16(gB2 + (k0 << 1), lB2);
        __syncthreads();
        bf16x8 af[4], bfr[4];
#pragma unroll
        for (int t = 0; t < 4; t++) {
            int ra = wm0 + t * 16 + lane15;
            af[t] = *(const bf16x8*)(As + ra * 64 + ((quad ^ swm) << 4));
            int rb = wn0 + t * 16 + lane15;
            bfr[t] = *(const bf16x8*)(Bs + rb * 64 + ((quad ^ swm) << 4));
        }
#pragma unroll
        for (int mt = 0; mt < 4; mt++)
#pragma unroll
            for (int nt = 0; nt < 4; nt++)
                acc[mt][nt] = __builtin_amdgcn_mfma_f32_16x16x32_bf16(
                    af[mt], bfr[nt], acc[mt][nt], 0, 0, 0);
    }

#pragma unroll
    for (int mt = 0; mt < 4; mt++) {
        int rowb = bm + wm0 + mt * 16 + quad * 4;
#pragma unroll
        for (int nt = 0; nt < 4; nt++) {
            int col = bn + wn0 + nt * 16 + lane15;
            f32x4 a = acc[mt][nt];
            C[(size_t)(rowb + 0) * N + col] = f2bf(a[0]);
            C[(size_t)(rowb + 1) * N + col] = f2bf(a[1]);
            C[(size_t)(rowb + 2) * N + col] = f2bf(a[2]);
            C[(size_t)(rowb + 3) * N + col] = f2bf(a[3]);
        }
    }
}

// ---------------------------------------------------------------------------
// GEMM1: A f32 (node features) with fused f32->bf16 staging convert; C is
// written PLANAR: cols 0..127 -> Ca[row][128], cols 128..255 -> Cb[row][128].
// ---------------------------------------------------------------------------
__global__ __launch_bounds__(256) void gemm_mfma_x_kernel(
        const float* __restrict__ A,
        const unsigned short* __restrict__ Bt,
        unsigned short* __restrict__ Ca,
        unsigned short* __restrict__ Cb) {
    const int K = 256;
    __shared__ char As[8192];
    __shared__ char Bs[8192];
    int tid = threadIdx.x;
    int bm = blockIdx.x * 128;
    int bn = blockIdx.y * 128;
    int lane = tid & 63, wave = tid >> 6;
    int lane15 = lane & 15, quad = lane >> 4;
    int wm0 = (wave >> 1) << 6;
    int wn0 = (wave & 1) << 6;

    int s1 = tid, s2 = tid + 256;
    int r1 = s1 >> 2, q1 = (s1 & 3) ^ ((r1 >> 1) & 3);
    int r2 = s2 >> 2, q2 = (s2 & 3) ^ ((r2 >> 1) & 3);
    const bool in1 = (bm + r1) < N_NODES;
    const bool in2 = (bm + r2) < N_NODES;
    const float* gA1 = A + (size_t)(bm + r1) * K + (q1 << 3);
    const float* gA2 = A + (size_t)(bm + r2) * K + (q2 << 3);
    const char* gB1 = (const char*)(Bt + (size_t)(bn + r1) * K) + (q1 << 4);
    const char* gB2 = (const char*)(Bt + (size_t)(bn + r2) * K) + (q2 << 4);
    char* lB1 = Bs + (wave << 10);
    char* lB2 = Bs + 4096 + (wave << 10);

    int swm = (lane15 >> 1) & 3;
    f32x4 acc[4][4];
#pragma unroll
    for (int mt = 0; mt < 4; mt++)
#pragma unroll
        for (int nt = 0; nt < 4; nt++)
            acc[mt][nt] = (f32x4){0.f, 0.f, 0.f, 0.f};

    const float4 z4 = make_float4(0.f, 0.f, 0.f, 0.f);
    for (int k0 = 0; k0 < K; k0 += 32) {
        __syncthreads();
        load16(gB1 + (k0 << 1), lB1);
        load16(gB2 + (k0 << 1), lB2);
        float4 a0 = in1 ? *(const float4*)(gA1 + k0)     : z4;
        float4 a1 = in1 ? *(const float4*)(gA1 + k0 + 4) : z4;
        float4 a2 = in2 ? *(const float4*)(gA2 + k0)     : z4;
        float4 a3 = in2 ? *(const float4*)(gA2 + k0 + 4) : z4;
        u16x8 u1 = { f2bf(a0.x), f2bf(a0.y), f2bf(a0.z), f2bf(a0.w),
                     f2bf(a1.x), f2bf(a1.y), f2bf(a1.z), f2bf(a1.w) };
        u16x8 u2 = { f2bf(a2.x), f2bf(a2.y), f2bf(a2.z), f2bf(a2.w),
                     f2bf(a3.x), f2bf(a3.y), f2bf(a3.z), f2bf(a3.w) };
        *(u16x8*)(As + s1 * 16) = u1;
        *(u16x8*)(As + s2 * 16) = u2;
        __syncthreads();
        bf16x8 af[4], bfr[4];
#pragma unroll
        for (int t = 0; t < 4; t++) {
            int ra = wm0 + t * 16 + lane15;
            af[t] = *(const bf16x8*)(As + ra * 64 + ((quad ^ swm) << 4));
            int rb = wn0 + t * 16 + lane15;
            bfr[t] = *(const bf16x8*)(Bs + rb * 64 + ((quad ^ swm) << 4));
        }
#pragma unroll
        for (int mt = 0; mt < 4; mt++)
#pragma unroll
            for (int nt = 0; nt < 4; nt++)
                acc[mt][nt] = __builtin_amdgcn_mfma_f32_16x16x32_bf16(
                    af[mt], bfr[nt], acc[mt][nt], 0, 0, 0);
    }

#pragma unroll
    for (int mt = 0; mt < 4; mt++) {
        int rowb = bm + wm0 + mt * 16 + quad * 4;
#pragma unroll
        for (int nt = 0; nt < 4; nt++) {
            int gc = bn + wn0 + nt * 16 + lane15;       // 0..255
            unsigned short* Cp = (gc & 128) ? Cb : Ca;
            int pc = gc & 127;
            f32x4 a = acc[mt][nt];
            Cp[(size_t)(rowb + 0) * 128 + pc] = f2bf(a[0]);
            Cp[(size_t)(rowb + 1) * 128 + pc] = f2bf(a[1]);
            Cp[(size_t)(rowb + 2) * 128 + pc] = f2bf(a[2]);
            Cp[(size_t)(rowb + 3) * 128 + pc] = f2bf(a[3]);
        }
    }
}

// ---------------------------------------------------------------------------
// agg1 over PLANAR h1: one launch; blocks [0,AGG1_HALF) do plane A (ch 0-127),
// the rest plane B (ch 128-255). Approx-linear dispatch => halved active
// working set per phase. wave/node, lane = 2ch, 8-edge unroll, ELU, bf16 out
// interleaved [node][256].
// ---------------------------------------------------------------------------
#define ACC2(V, W) \
    acc.x += bf2f(V.x) * W; acc.y += bf2f(V.y) * W;

__global__ __launch_bounds__(256) void agg1_kernel(const unsigned short* __restrict__ h1a,
                                                   const unsigned short* __restrict__ h1b,
                                                   const float* __restrict__ bias,
                                                   const int* __restrict__ rl,
                                                   const int* __restrict__ boff,
                                                   const int2* __restrict__ edge2,
                                                   const float* __restrict__ invdeg,
                                                   unsigned short* __restrict__ out) {
    int bx = blockIdx.x;
    int plane = (bx >= AGG1_HALF) ? 1 : 0;
    int node = (plane ? bx - AGG1_HALF : bx) * 4 + (threadIdx.x >> 6);
    // 12500*4 == 50000 exactly; no bounds check needed
    int lane = threadIdx.x & 63;
    const ushort2* hp = (const ushort2*)(plane ? h1b : h1a);
    int co = plane << 7;
    float id = invdeg[node];
    ushort2 sv = hp[(size_t)node * 64 + lane];
    float2 acc = make_float2(bf2f(sv.x) * id, bf2f(sv.y) * id);
    int e0 = rp(rl, boff, node);
    int e1 = rp(rl, boff, node + 1);
    int e = e0;
    for (; e + 7 < e1; e += 8) {
        int2 ed[8];
        ushort2 v[8];
#pragma unroll
        for (int j = 0; j < 8; j++) ed[j] = edge2[e + j];
#pragma unroll
        for (int j = 0; j < 8; j++) v[j] = hp[(size_t)ed[j].x * 64 + lane];
#pragma unroll
        for (int j = 0; j < 8; j++) {
            float w = __int_as_float(ed[j].y);
            ACC2(v[j], w);
        }
    }
    for (; e + 3 < e1; e += 4) {
        int2 ed[4];
        ushort2 v[4];
#pragma unroll
        for (int j = 0; j < 4; j++) ed[j] = edge2[e + j];
#pragma unroll
        for (int j = 0; j < 4; j++) v[j] = hp[(size_t)ed[j].x * 64 + lane];
#pragma unroll
        for (int j = 0; j < 4; j++) {
            float w = __int_as_float(ed[j].y);
            ACC2(v[j], w);
        }
    }
    for (; e < e1; e++) {
        int2 ed0 = edge2[e];
        float w0 = __int_as_float(ed0.y);
        ushort2 v0 = hp[(size_t)ed0.x * 64 + lane];
        ACC2(v0, w0);
    }
    float2 bb = ((const float2*)(bias + co))[lane];
    acc.x += bb.x; acc.y += bb.y;
    acc.x = acc.x > 0.f ? acc.x : expm1f(acc.x);
    acc.y = acc.y > 0.f ? acc.y : expm1f(acc.y);
    ushort2 o;
    o.x = f2bf(acc.x); o.y = f2bf(acc.y);
    ((ushort2*)(out + (size_t)node * 256 + co))[lane] = o;
}

// 128ch (conv2): wave/node, lane = 2ch, 8-edge unroll, bf16 output.
__global__ __launch_bounds__(256) void agg2_kernel(const unsigned short* __restrict__ h,
                                                   const float* __restrict__ bias,
                                                   const int* __restrict__ rl,
                                                   const int* __restrict__ boff,
                                                   const int2* __restrict__ edge2,
                                                   const float* __restrict__ invdeg,
                                                   unsigned short* __restrict__ out) {
    int node = blockIdx.x * 4 + (threadIdx.x >> 6);
    if (node >= N_NODES) return;
    int lane = threadIdx.x & 63;
    const ushort2* h2 = (const ushort2*)h;
    float id = invdeg[node];
    ushort2 sv = h2[(size_t)node * 64 + lane];
    float2 acc = make_float2(bf2f(sv.x) * id, bf2f(sv.y) * id);
    int e0 = rp(rl, boff, node);
    int e1 = rp(rl, boff, node + 1);
    int e = e0;
    for (; e + 7 < e1; e += 8) {
        int2 ed[8];
        ushort2 v[8];
#pragma unroll
        for (int j = 0; j < 8; j++) ed[j] = edge2[e + j];
#pragma unroll
        for (int j = 0; j < 8; j++) v[j] = h2[(size_t)ed[j].x * 64 + lane];
#pragma unroll
        for (int j = 0; j < 8; j++) {
            float w = __int_as_float(ed[j].y);
            ACC2(v[j], w);
        }
    }
    for (; e + 3 < e1; e += 4) {
        int2 ed[4];
        ushort2 v[4];
#pragma unroll
        for (int j = 0; j < 4; j++) ed[j] = edge2[e + j];
#pragma unroll
        for (int j = 0; j < 4; j++) v[j] = h2[(size_t)ed[j].x * 64 + lane];
#pragma unroll
        for (int j = 0; j < 4; j++) {
            float w = __int_as_float(ed[j].y);
            ACC2(v[j], w);
        }
    }
    for (; e < e1; e++) {
        int2 ed0 = edge2[e];
        float w0 = __int_as_float(ed0.y);
        ushort2 v0 = h2[(size_t)ed0.x * 64 + lane];
        ACC2(v0, w0);
    }
    float2 bb = ((const float2*)bias)[lane];
    acc.x += bb.x; acc.y += bb.y;
    ushort2 o;
    o.x = f2bf(acc.x); o.y = f2bf(acc.y);
    ((ushort2*)out)[(size_t)node * 64 + lane] = o;
}

// ---------------------------------------------------------------------------
// Global mean pool over sorted batch (bf16 input): 32-node chunks.
// ---------------------------------------------------------------------------
__global__ __launch_bounds__(128) void pool_kernel(const unsigned short* __restrict__ h,
                                                   const int* __restrict__ batch,
                                                   float* __restrict__ pool,
                                                   float* __restrict__ gcnt) {
    int c = threadIdx.x;
    int n0 = blockIdx.x * POOL_CHUNK;
    int n1 = n0 + POOL_CHUNK;
    if (n1 > N_NODES) n1 = N_NODES;
    if (n0 >= N_NODES) return;
    float run = 0.f, cnt = 0.f;
    int g = batch[n0];
    for (int n = n0; n < n1; n++) {
        int gn = batch[n];
        if (gn != g) {
            atomicAdd(&pool[g * OUT_CH + c], run);
            if (c == 0) atomicAdd(&gcnt[g], cnt);
            run = 0.f; cnt = 0.f; g = gn;
        }
        run += bf2f(h[(size_t)n * OUT_CH + c]);
        if (c == 0) cnt += 1.f;
    }
    atomicAdd(&pool[g * OUT_CH + c], run);
    if (c == 0) atomicAdd(&gcnt[g], cnt);
}

__global__ __launch_bounds__(256) void final_kernel(const float* __restrict__ pool,
                                                    const float* __restrict__ gcnt,
                                                    float* __restrict__ out) {
    int i = blockIdx.x * 256 + threadIdx.x;
    if (i < N_GRAPHS * OUT_CH)
        out[i] = pool[i] / fmaxf(gcnt[i >> 7], 1.0f);
}

// ---------------------------------------------------------------------------
extern "C" void kernel_launch(void* const* d_in, const int* in_sizes, int n_in,
                              void* d_out, int out_size, void* d_ws, size_t ws_size,
                              hipStream_t stream) {
    const float* x  = (const float*)d_in[0];
    const float* W1 = (const float*)d_in[1];
    const float* b1 = (const float*)d_in[2];
    const float* W2 = (const float*)d_in[3];
    const float* b2 = (const float*)d_in[4];
    const int*   ei = (const int*)d_in[5];
    const int*   batch = (const int*)d_in[6];
    float* out = (float*)d_out;

    // workspace layout (16B-aligned by construction)
    unsigned short* h1a = (unsigned short*)d_ws;                 // M_PAD*128 bf16 (plane A)
    unsigned short* h1b = h1a + (size_t)M_PAD * 128;             // M_PAD*128 bf16 (plane B)
    unsigned short* hBb = h1b + (size_t)M_PAD * 128;             // M_PAD*256 bf16
    unsigned short* h2b = hBb + (size_t)M_PAD * HID;             // M_PAD*128 bf16
    unsigned short* w1t = h2b + (size_t)M_PAD * OUT_CH;          // 256*256
    unsigned short* w2t = w1t + HID * IN_CH;                     // 128*256
    unsigned short* hcb = h1a;  // agg2 bf16 out aliases plane A (dead after gemm2)
    float* dinv   = (float*)(w2t + OUT_CH * HID);                // 50000
    float* invdeg = dinv + N_NODES;                              // 50000
    int*   rl     = (int*)(invdeg + N_NODES);                    // 50001 (pad 50016)
    int2*  edge2  = (int2*)(rl + 50016);                         // 800000 int2
    int*   cnt    = (int*)(edge2 + N_EDGES);                     // 50000 } zeroed
    int*   fillp  = cnt + N_NODES;                               // 50000 } zeroed
    float* gcnt   = (float*)(fillp + N_NODES);                   // 64    } zeroed
    float* pool   = gcnt + N_GRAPHS;                             // 8192  } zeroed
    int*   blocksum = (int*)(pool + N_GRAPHS * OUT_CH);          // 256
    int*   blockoff = blocksum + 256;                            // 256

    size_t zbytes = ((size_t)N_NODES * 2 + N_GRAPHS + (size_t)N_GRAPHS * OUT_CH) * 4;
    hipMemsetAsync(cnt, 0, zbytes, stream);

    // CSR build (+ weight convert merged into scan_b's launch)
    count_kernel<<<(N_EDGES + 255) / 256, 256, 0, stream>>>(ei, cnt);
    scan_a_kernel<<<SCAN_BLOCKS, 256, 0, stream>>>(cnt, rl, blocksum, dinv, invdeg);
    scanb_cvtw_kernel<<<385, 256, 0, stream>>>(blocksum, blockoff, W1, W2, w1t, w2t);
    fill_kernel<<<(N_EDGES + 255) / 256, 256, 0, stream>>>(ei, rl, blockoff, fillp, edge2, dinv);

    // conv1: fused-convert MFMA gemm (f32 x) -> planar bf16 h1, agg(+ELU) -> bf16 hB
    dim3 g1(M_PAD / 128, HID / 128);
    gemm_mfma_x_kernel<<<g1, 256, 0, stream>>>(x, w1t, h1a, h1b);
    agg1_kernel<<<2 * AGG1_HALF, 256, 0, stream>>>(h1a, h1b, b1, rl, blockoff,
                                                   edge2, invdeg, hBb);

    // conv2: MFMA gemm -> bf16 h2 (interleaved), aggregate -> bf16 hc
    dim3 g2(M_PAD / 128, OUT_CH / 128);
    gemm_mfma_kernel<<<g2, 256, 0, stream>>>(hBb, w2t, h2b, OUT_CH);
    agg2_kernel<<<(N_NODES + 3) / 4, 256, 0, stream>>>(h2b, b2, rl, blockoff,
                                                       edge2, invdeg, hcb);

    // mean pool
    pool_kernel<<<POOL_BLOCKS, 128, 0, stream>>>(hcb, batch, pool, gcnt);
    final_kernel<<<(N_GRAPHS * OUT_CH + 255) / 256, 256, 0, stream>>>(pool, gcnt, out);
}

// Round 10
// 321.900 us; speedup vs baseline: 1.0531x; 1.0531x over previous
//
#include <hip/hip_runtime.h>
#include <hip/hip_bf16.h>

#define N_NODES 50000
#define N_EDGES 800000
#define IN_CH 256
#define HID 256
#define OUT_CH 128
#define N_GRAPHS 64
#define SCAN_BLOCKS 196   // ceil(50001/256)
#define M_PAD 50048       // 391 * 128
#define POOL_CHUNK 32
#define POOL_BLOCKS ((N_NODES + POOL_CHUNK - 1) / POOL_CHUNK)

typedef __bf16 bf16x8 __attribute__((ext_vector_type(8)));
typedef float f32x4 __attribute__((ext_vector_type(4)));

// bf16 <-> f32 helpers (RNE on pack)
__device__ __forceinline__ float bf2f(unsigned short u) {
    union { unsigned int i; float f; } x; x.i = ((unsigned int)u) << 16; return x.f;
}
__device__ __forceinline__ unsigned short f2bf(float f) {
    union { float f; unsigned int i; } x; x.f = f;
    unsigned int r = x.i + 0x7FFFu + ((x.i >> 16) & 1u);
    return (unsigned short)(r >> 16);
}

__device__ __forceinline__ void load16(const void* g, void* l) {
    __builtin_amdgcn_global_load_lds(
        (const __attribute__((address_space(1))) void*)g,
        (__attribute__((address_space(3))) void*)l, 16, 0, 0);
}

// final rowptr = block-local exclusive + per-256-chunk offset
__device__ __forceinline__ int rp(const int* __restrict__ rl,
                                  const int* __restrict__ boff, int i) {
    return rl[i] + boff[i >> 8];
}

// ---------------------------------------------------------------------------
// CSR build: histogram, scan_a (block-local), merged scan_b+cvt_w, fill.
// ---------------------------------------------------------------------------
__global__ __launch_bounds__(256) void count_kernel(const int* __restrict__ ei,
                                                    int* __restrict__ cnt) {
    int e = blockIdx.x * 256 + threadIdx.x;
    if (e < N_EDGES) atomicAdd(&cnt[ei[N_EDGES + e]], 1);
}

__global__ __launch_bounds__(256) void scan_a_kernel(const int* __restrict__ cnt,
                                                     int* __restrict__ rl,
                                                     int* __restrict__ blocksum,
                                                     float* __restrict__ dinv,
                                                     float* __restrict__ invdeg) {
    __shared__ int tmp[256];
    int t = threadIdx.x;
    int i = blockIdx.x * 256 + t;
    int v = (i < N_NODES) ? cnt[i] : 0;
    int x = v;
    tmp[t] = x;
    __syncthreads();
#pragma unroll
    for (int off = 1; off < 256; off <<= 1) {
        int y = (t >= off) ? tmp[t - off] : 0;
        __syncthreads();
        x += y;
        tmp[t] = x;
        __syncthreads();
    }
    if (i <= N_NODES) rl[i] = x - v;
    if (i < N_NODES) {
        float d = (float)v + 1.0f;         // +1 self loop
        dinv[i] = rsqrtf(d);
        invdeg[i] = 1.0f / d;
    }
    if (t == 255) blocksum[blockIdx.x] = x;
}

// blocks 0..383: W1/W2 f32 -> bf16 transposed [N][K].
// block 384: exclusive scan of the 196 block sums -> blockoff.
__global__ __launch_bounds__(256) void scanb_cvtw_kernel(
        const int* __restrict__ blocksum, int* __restrict__ blockoff,
        const float* __restrict__ W1, const float* __restrict__ W2,
        unsigned short* __restrict__ w1t, unsigned short* __restrict__ w2t) {
    int t = threadIdx.x;
    if (blockIdx.x < 384) {
        int i = blockIdx.x * 256 + t;                 // 0 .. 98303
        if (i < HID * IN_CH) {                        // W1t[n][k] = W1[k][n]
            int n = i >> 8, k = i & 255;
            w1t[i] = f2bf(W1[k * HID + n]);
        } else {                                      // W2t[n][k] = W2[k][n]
            int j = i - HID * IN_CH;
            int n = j >> 8, k = j & 255;
            w2t[j] = f2bf(W2[k * OUT_CH + n]);
        }
        return;
    }
    __shared__ int tmp[256];
    int v = (t < SCAN_BLOCKS) ? blocksum[t] : 0;
    int x = v;
    tmp[t] = x;
    __syncthreads();
#pragma unroll
    for (int off = 1; off < 256; off <<= 1) {
        int y = (t >= off) ? tmp[t - off] : 0;
        __syncthreads();
        x += y;
        tmp[t] = x;
        __syncthreads();
    }
    if (t < SCAN_BLOCKS) blockoff[t] = x - v;
}

__global__ __launch_bounds__(256) void fill_kernel(const int* __restrict__ ei,
                                                   const int* __restrict__ rl,
                                                   const int* __restrict__ boff,
                                                   int* __restrict__ fillp,
                                                   int2* __restrict__ edge2,
                                                   const float* __restrict__ dinv) {
    int e = blockIdx.x * 256 + threadIdx.x;
    if (e >= N_EDGES) return;
    int s = ei[e];
    int d = ei[N_EDGES + e];
    int p = rp(rl, boff, d) + atomicAdd(&fillp[d], 1);
    float w = dinv[s] * dinv[d];
    edge2[p] = make_int2(s, __float_as_int(w));
}

// ---------------------------------------------------------------------------
// x f32 -> bf16, rows >= N_NODES zeroed (padding for the 128-tile GEMM).
// ---------------------------------------------------------------------------
__global__ __launch_bounds__(256) void cvt_x_kernel(const float* __restrict__ x,
                                                    unsigned short* __restrict__ xb) {
    int i = blockIdx.x * 256 + threadIdx.x;          // float4 index
    if (i >= M_PAD * (IN_CH / 4)) return;
    ushort4 o;
    if (i < N_NODES * (IN_CH / 4)) {
        float4 v = ((const float4*)x)[i];
        o.x = f2bf(v.x); o.y = f2bf(v.y); o.z = f2bf(v.z); o.w = f2bf(v.w);
    } else {
        o = make_ushort4(0, 0, 0, 0);
    }
    ((ushort4*)xb)[i] = o;
}

// ---------------------------------------------------------------------------
// bf16 MFMA GEMM: C = A @ Bt^T (interleaved C). 128x128 tile, 4 waves 2x2,
// each 64x64 = 4x4 mfma_f32_16x16x32_bf16. global_load_lds width=16 staging.
// ---------------------------------------------------------------------------
__global__ __launch_bounds__(256) void gemm_mfma_kernel(
        const unsigned short* __restrict__ A,
        const unsigned short* __restrict__ Bt,
        unsigned short* __restrict__ C,
        int N) {
    const int K = 256;
    __shared__ char As[8192];   // [128 rows][32 bf16], 16B chunks XOR-swizzled
    __shared__ char Bs[8192];
    int tid = threadIdx.x;
    int bm = blockIdx.x * 128;
    int bn = blockIdx.y * 128;
    int lane = tid & 63, wave = tid >> 6;
    int lane15 = lane & 15, quad = lane >> 4;
    int wm0 = (wave >> 1) << 6;
    int wn0 = (wave & 1) << 6;

    int s1 = tid, s2 = tid + 256;
    int r1 = s1 >> 2, q1 = (s1 & 3) ^ ((r1 >> 1) & 3);
    int r2 = s2 >> 2, q2 = (s2 & 3) ^ ((r2 >> 1) & 3);
    const char* gA1 = (const char*)(A + (size_t)(bm + r1) * K) + (q1 << 4);
    const char* gA2 = (const char*)(A + (size_t)(bm + r2) * K) + (q2 << 4);
    const char* gB1 = (const char*)(Bt + (size_t)(bn + r1) * K) + (q1 << 4);
    const char* gB2 = (const char*)(Bt + (size_t)(bn + r2) * K) + (q2 << 4);
    char* lA1 = As + (wave << 10);
    char* lA2 = As + 4096 + (wave << 10);
    char* lB1 = Bs + (wave << 10);
    char* lB2 = Bs + 4096 + (wave << 10);

    int swm = (lane15 >> 1) & 3;
    f32x4 acc[4][4];
#pragma unroll
    for (int mt = 0; mt < 4; mt++)
#pragma unroll
        for (int nt = 0; nt < 4; nt++)
            acc[mt][nt] = (f32x4){0.f, 0.f, 0.f, 0.f};

    for (int k0 = 0; k0 < K; k0 += 32) {
        __syncthreads();
        load16(gA1 + (k0 << 1), lA1);
        load16(gA2 + (k0 << 1), lA2);
        load16(gB1 + (k0 << 1), lB1);
        load16(gB2 + (k0 << 1), lB2);
        __syncthreads();
        bf16x8 af[4], bfr[4];
#pragma unroll
        for (int t = 0; t < 4; t++) {
            int ra = wm0 + t * 16 + lane15;
            af[t] = *(const bf16x8*)(As + ra * 64 + ((quad ^ swm) << 4));
            int rb = wn0 + t * 16 + lane15;
            bfr[t] = *(const bf16x8*)(Bs + rb * 64 + ((quad ^ swm) << 4));
        }
#pragma unroll
        for (int mt = 0; mt < 4; mt++)
#pragma unroll
            for (int nt = 0; nt < 4; nt++)
                acc[mt][nt] = __builtin_amdgcn_mfma_f32_16x16x32_bf16(
                    af[mt], bfr[nt], acc[mt][nt], 0, 0, 0);
    }

#pragma unroll
    for (int mt = 0; mt < 4; mt++) {
        int rowb = bm + wm0 + mt * 16 + quad * 4;
#pragma unroll
        for (int nt = 0; nt < 4; nt++) {
            int col = bn + wn0 + nt * 16 + lane15;
            f32x4 a = acc[mt][nt];
            C[(size_t)(rowb + 0) * N + col] = f2bf(a[0]);
            C[(size_t)(rowb + 1) * N + col] = f2bf(a[1]);
            C[(size_t)(rowb + 2) * N + col] = f2bf(a[2]);
            C[(size_t)(rowb + 3) * N + col] = f2bf(a[3]);
        }
    }
}

// ---------------------------------------------------------------------------
// GCN aggregation, 256ch (conv1): wave/node, lane = 4ch, bf16 ushort4
// gathers (512B/wave requests — measured better than 2x 256B), 8-edge
// unroll, f32 accumulate, ELU, bf16 output.
// ---------------------------------------------------------------------------
#define ACC4(V, W) \
    acc.x += bf2f(V.x) * W; acc.y += bf2f(V.y) * W; \
    acc.z += bf2f(V.z) * W; acc.w += bf2f(V.w) * W;

__global__ __launch_bounds__(256) void agg1_kernel(const unsigned short* __restrict__ h,
                                                   const float* __restrict__ bias,
                                                   const int* __restrict__ rl,
                                                   const int* __restrict__ boff,
                                                   const int2* __restrict__ edge2,
                                                   const float* __restrict__ invdeg,
                                                   unsigned short* __restrict__ out) {
    int node = blockIdx.x * 4 + (threadIdx.x >> 6);
    if (node >= N_NODES) return;
    int lane = threadIdx.x & 63;
    const ushort4* h4 = (const ushort4*)h;
    float id = invdeg[node];
    ushort4 sv = h4[(size_t)node * 64 + lane];
    float4 acc = make_float4(bf2f(sv.x) * id, bf2f(sv.y) * id,
                             bf2f(sv.z) * id, bf2f(sv.w) * id);
    int e0 = rp(rl, boff, node);
    int e1 = rp(rl, boff, node + 1);
    int e = e0;
    for (; e + 7 < e1; e += 8) {
        int2 ed[8];
        ushort4 v[8];
#pragma unroll
        for (int j = 0; j < 8; j++) ed[j] = edge2[e + j];
#pragma unroll
        for (int j = 0; j < 8; j++) v[j] = h4[(size_t)ed[j].x * 64 + lane];
#pragma unroll
        for (int j = 0; j < 8; j++) {
            float w = __int_as_float(ed[j].y);
            ACC4(v[j], w);
        }
    }
    for (; e + 3 < e1; e += 4) {
        int2 ed[4];
        ushort4 v[4];
#pragma unroll
        for (int j = 0; j < 4; j++) ed[j] = edge2[e + j];
#pragma unroll
        for (int j = 0; j < 4; j++) v[j] = h4[(size_t)ed[j].x * 64 + lane];
#pragma unroll
        for (int j = 0; j < 4; j++) {
            float w = __int_as_float(ed[j].y);
            ACC4(v[j], w);
        }
    }
    for (; e < e1; e++) {
        int2 ed0 = edge2[e];
        float w0 = __int_as_float(ed0.y);
        ushort4 v0 = h4[(size_t)ed0.x * 64 + lane];
        ACC4(v0, w0);
    }
    float4 bb = ((const float4*)bias)[lane];
    acc.x += bb.x; acc.y += bb.y; acc.z += bb.z; acc.w += bb.w;
    acc.x = acc.x > 0.f ? acc.x : expm1f(acc.x);
    acc.y = acc.y > 0.f ? acc.y : expm1f(acc.y);
    acc.z = acc.z > 0.f ? acc.z : expm1f(acc.z);
    acc.w = acc.w > 0.f ? acc.w : expm1f(acc.w);
    ushort4 o;
    o.x = f2bf(acc.x); o.y = f2bf(acc.y); o.z = f2bf(acc.z); o.w = f2bf(acc.w);
    ((ushort4*)out)[(size_t)node * 64 + lane] = o;
}

// 128ch (conv2): wave/node, lane = 2ch, 8-edge unroll, bf16 output.
#define ACC2(V, W) \
    acc.x += bf2f(V.x) * W; acc.y += bf2f(V.y) * W;

__global__ __launch_bounds__(256) void agg2_kernel(const unsigned short* __restrict__ h,
                                                   const float* __restrict__ bias,
                                                   const int* __restrict__ rl,
                                                   const int* __restrict__ boff,
                                                   const int2* __restrict__ edge2,
                                                   const float* __restrict__ invdeg,
                                                   unsigned short* __restrict__ out) {
    int node = blockIdx.x * 4 + (threadIdx.x >> 6);
    if (node >= N_NODES) return;
    int lane = threadIdx.x & 63;
    const ushort2* h2 = (const ushort2*)h;
    float id = invdeg[node];
    ushort2 sv = h2[(size_t)node * 64 + lane];
    float2 acc = make_float2(bf2f(sv.x) * id, bf2f(sv.y) * id);
    int e0 = rp(rl, boff, node);
    int e1 = rp(rl, boff, node + 1);
    int e = e0;
    for (; e + 7 < e1; e += 8) {
        int2 ed[8];
        ushort2 v[8];
#pragma unroll
        for (int j = 0; j < 8; j++) ed[j] = edge2[e + j];
#pragma unroll
        for (int j = 0; j < 8; j++) v[j] = h2[(size_t)ed[j].x * 64 + lane];
#pragma unroll
        for (int j = 0; j < 8; j++) {
            float w = __int_as_float(ed[j].y);
            ACC2(v[j], w);
        }
    }
    for (; e + 3 < e1; e += 4) {
        int2 ed[4];
        ushort2 v[4];
#pragma unroll
        for (int j = 0; j < 4; j++) ed[j] = edge2[e + j];
#pragma unroll
        for (int j = 0; j < 4; j++) v[j] = h2[(size_t)ed[j].x * 64 + lane];
#pragma unroll
        for (int j = 0; j < 4; j++) {
            float w = __int_as_float(ed[j].y);
            ACC2(v[j], w);
        }
    }
    for (; e < e1; e++) {
        int2 ed0 = edge2[e];
        float w0 = __int_as_float(ed0.y);
        ushort2 v0 = h2[(size_t)ed0.x * 64 + lane];
        ACC2(v0, w0);
    }
    float2 bb = ((const float2*)bias)[lane];
    acc.x += bb.x; acc.y += bb.y;
    ushort2 o;
    o.x = f2bf(acc.x); o.y = f2bf(acc.y);
    ((ushort2*)out)[(size_t)node * 64 + lane] = o;
}

// ---------------------------------------------------------------------------
// Global mean pool over sorted batch (bf16 input): 32-node chunks.
// ---------------------------------------------------------------------------
__global__ __launch_bounds__(128) void pool_kernel(const unsigned short* __restrict__ h,
                                                   const int* __restrict__ batch,
                                                   float* __restrict__ pool,
                                                   float* __restrict__ gcnt) {
    int c = threadIdx.x;
    int n0 = blockIdx.x * POOL_CHUNK;
    int n1 = n0 + POOL_CHUNK;
    if (n1 > N_NODES) n1 = N_NODES;
    if (n0 >= N_NODES) return;
    float run = 0.f, cnt = 0.f;
    int g = batch[n0];
    for (int n = n0; n < n1; n++) {
        int gn = batch[n];
        if (gn != g) {
            atomicAdd(&pool[g * OUT_CH + c], run);
            if (c == 0) atomicAdd(&gcnt[g], cnt);
            run = 0.f; cnt = 0.f; g = gn;
        }
        run += bf2f(h[(size_t)n * OUT_CH + c]);
        if (c == 0) cnt += 1.f;
    }
    atomicAdd(&pool[g * OUT_CH + c], run);
    if (c == 0) atomicAdd(&gcnt[g], cnt);
}

__global__ __launch_bounds__(256) void final_kernel(const float* __restrict__ pool,
                                                    const float* __restrict__ gcnt,
                                                    float* __restrict__ out) {
    int i = blockIdx.x * 256 + threadIdx.x;
    if (i < N_GRAPHS * OUT_CH)
        out[i] = pool[i] / fmaxf(gcnt[i >> 7], 1.0f);
}

// ---------------------------------------------------------------------------
extern "C" void kernel_launch(void* const* d_in, const int* in_sizes, int n_in,
                              void* d_out, int out_size, void* d_ws, size_t ws_size,
                              hipStream_t stream) {
    const float* x  = (const float*)d_in[0];
    const float* W1 = (const float*)d_in[1];
    const float* b1 = (const float*)d_in[2];
    const float* W2 = (const float*)d_in[3];
    const float* b2 = (const float*)d_in[4];
    const int*   ei = (const int*)d_in[5];
    const int*   batch = (const int*)d_in[6];
    float* out = (float*)d_out;

    // workspace layout (16B-aligned by construction)
    unsigned short* xb  = (unsigned short*)d_ws;                 // M_PAD*256 bf16
    unsigned short* h1b = xb  + (size_t)M_PAD * IN_CH;           // M_PAD*256 bf16
    unsigned short* hBb = h1b + (size_t)M_PAD * HID;             // M_PAD*256 bf16
    unsigned short* h2b = hBb + (size_t)M_PAD * HID;             // M_PAD*128 bf16
    unsigned short* w1t = h2b + (size_t)M_PAD * OUT_CH;          // 256*256
    unsigned short* w2t = w1t + HID * IN_CH;                     // 128*256
    unsigned short* hcb = xb;   // agg2 bf16 out aliases xb (dead after gemm1)
    float* dinv   = (float*)(w2t + OUT_CH * HID);                // 50000
    float* invdeg = dinv + N_NODES;                              // 50000
    int*   rl     = (int*)(invdeg + N_NODES);                    // 50001 (pad 50016)
    int2*  edge2  = (int2*)(rl + 50016);                         // 800000 int2
    int*   cnt    = (int*)(edge2 + N_EDGES);                     // 50000 } zeroed
    int*   fillp  = cnt + N_NODES;                               // 50000 } zeroed
    float* gcnt   = (float*)(fillp + N_NODES);                   // 64    } zeroed
    float* pool   = gcnt + N_GRAPHS;                             // 8192  } zeroed
    int*   blocksum = (int*)(pool + N_GRAPHS * OUT_CH);          // 256
    int*   blockoff = blocksum + 256;                            // 256

    size_t zbytes = ((size_t)N_NODES * 2 + N_GRAPHS + (size_t)N_GRAPHS * OUT_CH) * 4;
    hipMemsetAsync(cnt, 0, zbytes, stream);

    // CSR build (+ weight convert merged into scan_b's launch)
    count_kernel<<<(N_EDGES + 255) / 256, 256, 0, stream>>>(ei, cnt);
    scan_a_kernel<<<SCAN_BLOCKS, 256, 0, stream>>>(cnt, rl, blocksum, dinv, invdeg);
    scanb_cvtw_kernel<<<385, 256, 0, stream>>>(blocksum, blockoff, W1, W2, w1t, w2t);
    fill_kernel<<<(N_EDGES + 255) / 256, 256, 0, stream>>>(ei, rl, blockoff, fillp, edge2, dinv);

    // conv1: cvt_x -> bf16, MFMA gemm -> bf16 h1, aggregate(+ELU) -> bf16 hB
    cvt_x_kernel<<<(M_PAD * (IN_CH / 4) + 255) / 256, 256, 0, stream>>>(x, xb);
    dim3 g1(M_PAD / 128, HID / 128);
    gemm_mfma_kernel<<<g1, 256, 0, stream>>>(xb, w1t, h1b, HID);
    agg1_kernel<<<(N_NODES + 3) / 4, 256, 0, stream>>>(h1b, b1, rl, blockoff,
                                                       edge2, invdeg, hBb);

    // conv2: MFMA gemm -> bf16 h2, aggregate -> bf16 hc
    dim3 g2(M_PAD / 128, OUT_CH / 128);
    gemm_mfma_kernel<<<g2, 256, 0, stream>>>(hBb, w2t, h2b, OUT_CH);
    agg2_kernel<<<(N_NODES + 3) / 4, 256, 0, stream>>>(h2b, b2, rl, blockoff,
                                                       edge2, invdeg, hcb);

    // mean pool
    pool_kernel<<<POOL_BLOCKS, 128, 0, stream>>>(hcb, batch, pool, gcnt);
    final_kernel<<<(N_GRAPHS * OUT_CH + 255) / 256, 256, 0, stream>>>(pool, gcnt, out);
}